// Round 13
// baseline (316.968 us; speedup 1.0000x reference)
//
#include <hip/hip_runtime.h>
#include <hip/hip_bf16.h>

#define EPSBN 1e-5f
#define NGRAPH 512
#define SCAN_NB 128

typedef __attribute__((ext_vector_type(8))) short bf16x8;
typedef __attribute__((ext_vector_type(4))) float f32x4;

__device__ inline short f2bf(float f) {  // RNE float->bf16
    unsigned u = __builtin_bit_cast(unsigned, f);
    u += 0x7fffu + ((u >> 16) & 1u);
    return (short)(u >> 16);
}
__device__ inline float bf2f(short s) {
    unsigned u = ((unsigned)(unsigned short)s) << 16;
    return __builtin_bit_cast(float, u);
}
// Real XCD id (m09). Correctness-safe uses only: privatized copies summed later.
__device__ inline int xcd_id() {
    int x;
    asm volatile("s_getreg_b32 %0, hwreg(HW_REG_XCC_ID, 0, 4)" : "=s"(x));
    return x & 7;
}

// ---------------------------------------------------------------------------
// CSR build step 1: 8-copy histogram of dst (per-XCD privatized)
// ---------------------------------------------------------------------------
__global__ void __launch_bounds__(256) k_hist8(
    const int* __restrict__ dst, int* __restrict__ hist8, int E, int Npad)
{
    int* h = hist8 + xcd_id() * Npad;
    const int stride = gridDim.x * 256;
    for (int e = blockIdx.x * 256 + threadIdx.x; e < E; e += stride)
        atomicAdd(&h[dst[e]], 1);
}

// scan phase 1: per-block partial sums of (8-copy summed) hist
__global__ void __launch_bounds__(256) k_scan1(
    const int* __restrict__ hist8, int* __restrict__ blocksum, int N, int Npad)
{
    __shared__ int red[256];
    const int C = (N + SCAN_NB - 1) / SCAN_NB;
    const int b = blockIdx.x, t = threadIdx.x;
    const int lo = b * C, hi = min(lo + C, N);
    int s = 0;
    for (int i = lo + t; i < hi; i += 256) {
        int v = 0;
        #pragma unroll
        for (int c = 0; c < 8; c++) v += hist8[c * Npad + i];
        s += v;
    }
    red[t] = s;
    __syncthreads();
    for (int off = 128; off; off >>= 1) {
        if (t < off) red[t] += red[t + off];
        __syncthreads();
    }
    if (t == 0) blocksum[b] = red[0];
}

// scan phase 2: per-block offset from blocksum + local scan -> row_off/cursor
__global__ void __launch_bounds__(256) k_scan3(
    const int* __restrict__ hist8, const int* __restrict__ blocksum,
    int* __restrict__ row_off, int* __restrict__ cursor, int N, int Npad)
{
    __shared__ int red[256];
    __shared__ int boff_s;
    const int C = (N + SCAN_NB - 1) / SCAN_NB;
    const int b = blockIdx.x, t = threadIdx.x;
    const int lo = b * C, hi = min(lo + C, N);
    if (t == 0) {
        int acc = 0;
        for (int i = 0; i < b; i++) acc += blocksum[i];
        boff_s = acc;
        if (b == SCAN_NB - 1) {
            int tot = acc;
            for (int i = b; i < SCAN_NB; i++) tot += blocksum[i];
            row_off[N] = tot;
        }
    }
    const int TC = (C + 255) / 256;
    const int s0 = lo + t * TC;
    const int s1 = min(s0 + TC, hi);
    auto hsum = [&](int i) {
        int v = 0;
        #pragma unroll
        for (int c = 0; c < 8; c++) v += hist8[c * Npad + i];
        return v;
    };
    int s = 0;
    for (int i = s0; i < s1; i++) s += hsum(i);
    red[t] = s;
    __syncthreads();
    for (int off = 1; off < 256; off <<= 1) {
        int u = (t >= off) ? red[t - off] : 0;
        __syncthreads();
        red[t] += u;
        __syncthreads();
    }
    int run = boff_s + red[t] - s;
    for (int i = s0; i < s1; i++) {
        row_off[i] = run;
        cursor[i] = run;
        run += hsum(i);
    }
}

// CSR build step 3: plain grid-stride scatter (measured floor ~55us,
// writeback-bound: 64B HBM burst per random 4B write; NT store made it worse)
__global__ void __launch_bounds__(256) k_scatter(
    const int* __restrict__ src, const int* __restrict__ dst,
    int* __restrict__ cursor, int* __restrict__ csr, int E)
{
    for (int e = blockIdx.x * 256 + threadIdx.x; e < E; e += gridDim.x * 256) {
        int d = dst[e];
        int p = atomicAdd(&cursor[d], 1);
        csr[p] = src[e];
    }
}

// ---------------------------------------------------------------------------
// per-graph node counts via binary search on sorted batch (no atomics)
// ---------------------------------------------------------------------------
__device__ inline int lbound(const int* __restrict__ a, int n, int v) {
    int lo = 0, hi = n;
    while (lo < hi) {
        int mid = (lo + hi) >> 1;
        if (a[mid] < v) lo = mid + 1; else hi = mid;
    }
    return lo;
}
__global__ void __launch_bounds__(256) k_gcnt_bs(
    const int* __restrict__ batch, float* __restrict__ gcnt, int N)
{
    int g = blockIdx.x * 256 + threadIdx.x;
    if (g < NGRAPH)
        gcnt[g] = (float)(lbound(batch, N, g + 1) - lbound(batch, N, g));
}

// ---------------------------------------------------------------------------
// Gather-aggregate, ONE WAVE PER ROW: 64 lanes = NB neighbor-groups x FL
// feature-lanes (16B each). Uniform loop (no divergence straggler), length
// ceil(deg/NB); shfl_xor tree reduces across neighbor groups. fp32 accum.
// ---------------------------------------------------------------------------
template <int F>
__global__ void __launch_bounds__(256) k_gatherw(
    const short* __restrict__ feat, const int* __restrict__ row_off,
    const int* __restrict__ csr, short* __restrict__ aggb, int N)
{
    constexpr int FL = F / 8;          // lanes covering one feature row
    constexpr int NB = 64 / FL;        // neighbors processed in parallel
    const int wid = threadIdx.x >> 6;
    const int lane = threadIdx.x & 63;
    const int fl = lane % FL;
    const int nbr = lane / FL;
    const int row = blockIdx.x * 4 + wid;
    if (row >= N) return;
    const int s0 = row_off[row];
    const int s1 = row_off[row + 1];
    const short* fbase = feat + fl * 8;

    float acc[8];
    #pragma unroll
    for (int i = 0; i < 8; i++) acc[i] = 0.f;
    for (int p = s0 + nbr; p < s1; p += NB) {
        int sA = csr[p];
        bf16x8 va = *(const bf16x8*)&fbase[(long long)sA * F];
        #pragma unroll
        for (int i = 0; i < 8; i++) acc[i] += bf2f(va[i]);
    }
    // reduce across neighbor groups (lanes differing above fl bits)
    #pragma unroll
    for (int off = FL; off < 64; off <<= 1) {
        #pragma unroll
        for (int i = 0; i < 8; i++)
            acc[i] += __shfl_xor(acc[i], off, 64);
    }
    if (nbr == 0) {
        short o[8];
        #pragma unroll
        for (int i = 0; i < 8; i++) o[i] = f2bf(acc[i]);
        *(bf16x8*)&aggb[(long long)row * F + fl * 8] = *(bf16x8*)o;
    }
}

// ---------------------------------------------------------------------------
// fp32 -> bf16 convert
// ---------------------------------------------------------------------------
__global__ void __launch_bounds__(256) k_cvt(
    const float* __restrict__ in, short* __restrict__ out, long long n4)
{
    long long i = (long long)blockIdx.x * 256 + threadIdx.x;
    if (i >= n4) return;
    float4 v = *(const float4*)&in[i * 4];
    short4 o = make_short4(f2bf(v.x), f2bf(v.y), f2bf(v.z), f2bf(v.w));
    *(short4*)&out[i * 4] = o;
}

// ---------------------------------------------------------------------------
// Weight prep (both matrices of a layer in one launch)
// ---------------------------------------------------------------------------
template <int K, int F, bool AFF>
__global__ void __launch_bounds__(64) k_wprep2(
    const float* __restrict__ Wl, const float* __restrict__ Wr,
    const float* __restrict__ a, const float* __restrict__ c,
    const float* __restrict__ bias,
    short* __restrict__ Wlt, short* __restrict__ Wrt,
    float* __restrict__ cvl, float* __restrict__ cvr)
{
    int j = blockIdx.x * 64 + threadIdx.x;
    const bool second = j >= F;
    const int jj = second ? j - F : j;
    if (jj >= F || j >= 2 * F) return;
    const float* W = second ? Wr : Wl;
    short* Wt = second ? Wrt : Wlt;
    float cv = (second && bias) ? bias[jj] : 0.f;
    for (int k = 0; k < K; k++) {
        float w = W[k * F + jj];
        float aa = 1.f;
        if constexpr (AFF) {
            aa = a[k];
            cv += c[k] * w;
        }
        Wt[jj * K + k] = f2bf(aa * w);
    }
    if (second) cvr[jj] = cv; else cvl[jj] = cv;
}

// ---------------------------------------------------------------------------
// MFMA bf16 GEMM with fused epilogue.
//   v = [relu]( A@Wt' + DUAL*invc*(A2@Wt2') + HASBASE*invc*base + cvec )
//   POOL: atomicAdd v into this XCD's praw copy (8-copy privatized)
// ---------------------------------------------------------------------------
template <int K, int FOUT, bool DUAL, bool HASBASE, bool FINAL, bool OUTBF16,
          bool POOL>
__global__ void __launch_bounds__(256) k_mgemm(
    const short* __restrict__ A, const short* __restrict__ A2,
    const short* __restrict__ Wt, const short* __restrict__ Wt2,
    const float* __restrict__ cvec, const short* __restrict__ base,
    const int* __restrict__ row_off, void* outv,
    float* __restrict__ s_out, float* __restrict__ q_out,
    const int* __restrict__ batchp, float* __restrict__ praw8, int N)
{
    constexpr int KS = K / 32;
    constexpr int NCT = FOUT / 16;
    const int lane = threadIdx.x & 63;
    const int wid = threadIdx.x >> 6;
    const int g = lane >> 4;
    const int mi = lane & 15;
    const int RT = (N + 15) >> 4;
    const int nw = gridDim.x * 4;
    float* outf = (float*)outv;
    short* outb = (short*)outv;
    float* pr = nullptr;
    if constexpr (POOL) pr = praw8 + (size_t)xcd_id() * NGRAPH * 32;

    float st_s[FINAL ? NCT : 1];
    float st_q[FINAL ? NCT : 1];
    if constexpr (FINAL) {
        #pragma unroll
        for (int ct = 0; ct < NCT; ct++) { st_s[ct] = 0.f; st_q[ct] = 0.f; }
    }

    for (int rt = blockIdx.x * 4 + wid; rt < RT; rt += nw) {
        const int m0 = rt * 16;
        int arow = m0 + mi;
        if (arow >= N) arow = N - 1;

        bf16x8 af[KS];
        bf16x8 af2[DUAL ? KS : 1];
        const short* ap = A + (long long)arow * K;
        #pragma unroll
        for (int s = 0; s < KS; s++)
            af[s] = *(const bf16x8*)(ap + s * 32 + g * 8);
        if constexpr (DUAL) {
            const short* ap2 = A2 + (long long)arow * K;
            #pragma unroll
            for (int s = 0; s < KS; s++)
                af2[s] = *(const bf16x8*)(ap2 + s * 32 + g * 8);
        }

        float invc[4];
        if constexpr (DUAL || HASBASE) {
            #pragma unroll
            for (int r = 0; r < 4; r++) {
                int row = m0 + 4 * g + r;
                int cnt = 1;
                if (row < N) cnt = max(row_off[row + 1] - row_off[row], 1);
                invc[r] = 1.f / (float)cnt;
            }
        }
        int bidx[4];
        if constexpr (POOL) {
            #pragma unroll
            for (int r = 0; r < 4; r++) {
                int row = m0 + 4 * g + r;
                bidx[r] = (row < N) ? batchp[row] : -1;
            }
        }

        #pragma unroll
        for (int ct = 0; ct < NCT; ct++) {
            f32x4 acc = {0.f, 0.f, 0.f, 0.f};
            f32x4 acc2 = {0.f, 0.f, 0.f, 0.f};
            const short* bp = Wt + (long long)(ct * 16 + mi) * K;
            #pragma unroll
            for (int s = 0; s < KS; s++) {
                bf16x8 bf = *(const bf16x8*)(bp + s * 32 + g * 8);
                acc = __builtin_amdgcn_mfma_f32_16x16x32_bf16(af[s], bf, acc, 0, 0, 0);
                if constexpr (DUAL) {
                    bf16x8 bf2 = *(const bf16x8*)(Wt2 + (long long)(ct * 16 + mi) * K + s * 32 + g * 8);
                    acc2 = __builtin_amdgcn_mfma_f32_16x16x32_bf16(af2[s], bf2, acc2, 0, 0, 0);
                }
            }
            float cv = cvec[ct * 16 + mi];
            float sl = 0.f, ql = 0.f;
            #pragma unroll
            for (int r = 0; r < 4; r++) {
                int row = m0 + 4 * g + r;
                if (row < N) {
                    float v = acc[r] + cv;
                    if constexpr (DUAL) v = fmaf(invc[r], acc2[r], v);
                    if constexpr (HASBASE)
                        v = fmaf(invc[r], bf2f(base[(long long)row * FOUT + ct * 16 + mi]), v);
                    if constexpr (FINAL) v = fmaxf(v, 0.f);
                    if constexpr (POOL) {
                        atomicAdd(&pr[bidx[r] * FOUT + ct * 16 + mi], v);
                    } else if constexpr (OUTBF16) {
                        outb[(long long)row * FOUT + ct * 16 + mi] = f2bf(v);
                    } else {
                        outf[(long long)row * FOUT + ct * 16 + mi] = v;
                    }
                    if constexpr (FINAL) { sl += v; ql += v * v; }
                }
            }
            if constexpr (FINAL) {
                sl += __shfl_xor(sl, 16, 64);
                sl += __shfl_xor(sl, 32, 64);
                ql += __shfl_xor(ql, 16, 64);
                ql += __shfl_xor(ql, 32, 64);
                st_s[ct] += sl;
                st_q[ct] += ql;
            }
        }
    }

    if constexpr (FINAL) {
        __shared__ float redS[4][NCT][16];
        __shared__ float redQ[4][NCT][16];
        if (lane < 16) {
            #pragma unroll
            for (int ct = 0; ct < NCT; ct++) {
                redS[wid][ct][lane] = st_s[ct];
                redQ[wid][ct][lane] = st_q[ct];
            }
        }
        __syncthreads();
        if (wid == 0 && lane < 16) {
            #pragma unroll
            for (int ct = 0; ct < NCT; ct++) {
                float s = redS[0][ct][lane] + redS[1][ct][lane] +
                          redS[2][ct][lane] + redS[3][ct][lane];
                float q = redQ[0][ct][lane] + redQ[1][ct][lane] +
                          redQ[2][ct][lane] + redQ[3][ct][lane];
                atomicAdd(&s_out[ct * 16 + lane], s);
                atomicAdd(&q_out[ct * 16 + lane], q);
            }
        }
    }
}

// ---------------------------------------------------------------------------
// BN affine finalize
// ---------------------------------------------------------------------------
__global__ void k_finalize(const float* __restrict__ s, const float* __restrict__ q,
                           const float* __restrict__ g, const float* __restrict__ be,
                           float* __restrict__ a, float* __restrict__ c,
                           int F, float invN)
{
    int j = threadIdx.x;
    if (j < F) {
        float mu = s[j] * invN;
        float var = q[j] * invN - mu * mu;
        float aj = g[j] / sqrtf(var + EPSBN);
        a[j] = aj;
        c[j] = be[j] - mu * aj;
    }
}

// ---------------------------------------------------------------------------
// Per-graph MLP (sums 8 praw copies, applies BN3 affine on load)
// ---------------------------------------------------------------------------
__global__ void __launch_bounds__(128) k_mlp(
    const float* __restrict__ praw8, const float* __restrict__ a3,
    const float* __restrict__ c3, const float* __restrict__ gcnt,
    const float* __restrict__ Wf1, const float* __restrict__ bf1,
    const float* __restrict__ Wf2, const float* __restrict__ bf2,
    const float* __restrict__ Wf3, const float* __restrict__ bf3,
    float* __restrict__ out)
{
    __shared__ float p[32], h1[128], h2[64];
    int g = blockIdx.x, t = threadIdx.x;
    if (t < 32) {
        float s = 0.f;
        #pragma unroll
        for (int c = 0; c < 8; c++)
            s += praw8[(size_t)c * NGRAPH * 32 + g * 32 + t];
        p[t] = a3[t] * s + gcnt[g] * c3[t];
    }
    __syncthreads();
    {
        float acc = bf1[t];
        #pragma unroll
        for (int k = 0; k < 32; k++) acc += p[k] * Wf1[k * 128 + t];
        h1[t] = fmaxf(acc, 0.f);
    }
    __syncthreads();
    if (t < 64) {
        float acc = bf2[t];
        #pragma unroll
        for (int k = 0; k < 128; k++) acc += h1[k] * Wf2[k * 64 + t];
        h2[t] = fmaxf(acc, 0.f);
    }
    __syncthreads();
    if (t < 2) {
        float acc = bf3[t];
        #pragma unroll
        for (int k = 0; k < 64; k++) acc += h2[k] * Wf3[k * 2 + t];
        out[g * 2 + t] = acc;
    }
}

// ---------------------------------------------------------------------------
extern "C" void kernel_launch(void* const* d_in, const int* in_sizes, int n_in,
                              void* d_out, int out_size, void* d_ws, size_t ws_size,
                              hipStream_t stream)
{
    const float* x     = (const float*)d_in[0];
    const int*   ei    = (const int*)d_in[1];
    const int*   batch = (const int*)d_in[2];
    const float* W1l = (const float*)d_in[3];
    const float* b1  = (const float*)d_in[4];
    const float* W1r = (const float*)d_in[5];
    const float* g1  = (const float*)d_in[6];
    const float* be1 = (const float*)d_in[7];
    const float* W2l = (const float*)d_in[8];
    const float* b2  = (const float*)d_in[9];
    const float* W2r = (const float*)d_in[10];
    const float* g2  = (const float*)d_in[11];
    const float* be2 = (const float*)d_in[12];
    const float* W3l = (const float*)d_in[13];
    const float* b3  = (const float*)d_in[14];
    const float* W3r = (const float*)d_in[15];
    const float* g3  = (const float*)d_in[16];
    const float* be3 = (const float*)d_in[17];
    const float* Wf1 = (const float*)d_in[18];
    const float* bf1 = (const float*)d_in[19];
    const float* Wf2 = (const float*)d_in[20];
    const float* bf2 = (const float*)d_in[21];
    const float* Wf3 = (const float*)d_in[22];
    const float* bf3 = (const float*)d_in[23];

    const int N = in_sizes[0] / 64;
    const int E = in_sizes[1] / 2;
    const int Npad = (N + 255) & ~255;
    const int* src = ei;
    const int* dst = ei + E;

    // ---- workspace layout (zoned aliasing; zeroed accumulators contiguous) --
    char* ws = (char*)d_ws;
    size_t off = 0;
    auto alloc = [&](size_t bytes) {
        size_t o = off;
        off += (bytes + 511) & ~(size_t)511;
        return o;
    };
    const size_t o_rowoff = alloc((size_t)(N + 1) * 4);
    const size_t o_cursor = alloc((size_t)N * 4);
    const size_t o_bsum   = alloc(SCAN_NB * 4);
    const size_t o_csr    = alloc((size_t)E * 4);
    const size_t o_zoneB  = alloc((size_t)N * 128);  // xb -> y2b (bf16)
    const size_t o_zoneC  = alloc((size_t)N * 128);  // aggb -> t2b (bf16)
    const size_t o_zoneD  = alloc((size_t)N * 256);  // t1b -> y3b (bf16)
    const size_t o_zoneE  = alloc((size_t)N * 128);  // m2b -> m3b (bf16)
    const size_t o_aff    = alloc(448 * 4);
    const size_t o_cvec   = alloc(512 * 4);
    const size_t o_wt     = alloc((8192 * 4 + 2048 * 2) * 2);
    const size_t o_gcnt   = alloc((size_t)NGRAPH * 4);      // overwritten fully
    // ---- zero zone (single memset) ----
    const size_t o_zero0  = off;
    const size_t o_hist8  = alloc((size_t)Npad * 8 * 4);
    const size_t o_stats  = alloc(448 * 4);
    const size_t o_praw8  = alloc((size_t)NGRAPH * 32 * 4 * 8);
    const size_t zero_len = off - o_zero0;
    (void)ws_size;

    int* row_off = (int*)(ws + o_rowoff);
    int* hist8   = (int*)(ws + o_hist8);
    int* cursor  = (int*)(ws + o_cursor);
    int* bsum    = (int*)(ws + o_bsum);
    int* csr     = (int*)(ws + o_csr);
    short* xb   = (short*)(ws + o_zoneB);
    short* y2b  = (short*)(ws + o_zoneB);       // after xb dead
    short* aggb = (short*)(ws + o_zoneC);
    short* t2b  = (short*)(ws + o_zoneC);       // after aggb dead
    short* t1b  = (short*)(ws + o_zoneD);
    short* y3b  = (short*)(ws + o_zoneD);       // after t1b dead
    short* m2b  = (short*)(ws + o_zoneE);
    short* m3b  = (short*)(ws + o_zoneE);       // after m2b dead
    float* praw8 = (float*)(ws + o_praw8);
    float* gcnt  = (float*)(ws + o_gcnt);
    float* s1 = (float*)(ws + o_stats);
    float* q1 = s1 + 128;
    float* s2 = q1 + 128;
    float* q2 = s2 + 64;
    float* s3 = q2 + 64;
    float* q3 = s3 + 32;
    float* a1 = (float*)(ws + o_aff);
    float* c1 = a1 + 128;
    float* a2 = c1 + 128;
    float* c2 = a2 + 64;
    float* a3 = c2 + 64;
    float* c3 = a3 + 32;
    float* cv1l = (float*)(ws + o_cvec);         // dummy
    float* cv1r = cv1l + 128;
    float* cv2l = cv1r + 128;
    float* cv2r = cv2l + 64;
    float* cv3l = cv2r + 64;
    float* cv3r = cv3l + 32;
    short* W1l_t = (short*)(ws + o_wt);          // 128x64
    short* W1r_t = W1l_t + 8192;
    short* W2l_t = W1r_t + 8192;
    short* W2r_t = W2l_t + 8192;
    short* W3l_t = W2r_t + 8192;
    short* W3r_t = W3l_t + 2048;

    const float invN = 1.0f / (float)N;
    const int MG = 512;
    const int GW = (N + 3) / 4;   // gather: one wave per row, 4 waves/block

    // ---- zero accumulators (one memset, ~2.4 MB) ----
    hipMemsetAsync(ws + o_zero0, 0, zero_len, stream);

    // ---- CSR build ----
    k_hist8<<<2048, 256, 0, stream>>>(dst, hist8, E, Npad);
    k_scan1<<<SCAN_NB, 256, 0, stream>>>(hist8, bsum, N, Npad);
    k_scan3<<<SCAN_NB, 256, 0, stream>>>(hist8, bsum, row_off, cursor, N, Npad);
    k_scatter<<<2048, 256, 0, stream>>>(src, dst, cursor, csr, E);
    k_gcnt_bs<<<2, 256, 0, stream>>>(batch, gcnt, N);

    // ---- prep: x->bf16, layer-1 weights ----
    k_cvt<<<(int)(((long long)N * 16 + 255) / 256), 256, 0, stream>>>(
        x, xb, (long long)N * 16);
    k_wprep2<64, 128, false><<<4, 64, 0, stream>>>(
        W1l, W1r, nullptr, nullptr, b1, W1l_t, W1r_t, cv1l, cv1r);

    // ---- layer 1: t1 = relu(x@W1r + invc*(agg@W1l) + b1) ----
    k_gatherw<64><<<GW, 256, 0, stream>>>(xb, row_off, csr, aggb, N);
    k_mgemm<64, 128, true, false, true, true, false><<<MG, 256, 0, stream>>>(
        xb, aggb, W1r_t, W1l_t, cv1r, nullptr, row_off, t1b, s1, q1,
        nullptr, nullptr, N);
    k_finalize<<<1, 128, 0, stream>>>(s1, q1, g1, be1, a1, c1, 128, invN);

    // ---- layer 2 ----
    k_wprep2<128, 64, true><<<2, 64, 0, stream>>>(
        W2l, W2r, a1, c1, b2, W2l_t, W2r_t, cv2l, cv2r);
    k_mgemm<128, 64, false, false, false, true, false><<<MG, 256, 0, stream>>>(
        t1b, nullptr, W2l_t, nullptr, cv2l, nullptr, row_off, y2b,
        nullptr, nullptr, nullptr, nullptr, N);
    k_gatherw<64><<<GW, 256, 0, stream>>>(y2b, row_off, csr, m2b, N);
    k_mgemm<128, 64, false, true, true, true, false><<<MG, 256, 0, stream>>>(
        t1b, nullptr, W2r_t, nullptr, cv2r, m2b, row_off, t2b, s2, q2,
        nullptr, nullptr, N);
    k_finalize<<<1, 64, 0, stream>>>(s2, q2, g2, be2, a2, c2, 64, invN);

    // ---- layer 3 ----
    k_wprep2<64, 32, true><<<1, 64, 0, stream>>>(
        W3l, W3r, a2, c2, b3, W3l_t, W3r_t, cv3l, cv3r);
    k_mgemm<64, 32, false, false, false, true, false><<<MG, 256, 0, stream>>>(
        t2b, nullptr, W3l_t, nullptr, cv3l, nullptr, row_off, y3b,
        nullptr, nullptr, nullptr, nullptr, N);
    k_gatherw<32><<<GW, 256, 0, stream>>>(y3b, row_off, csr, m3b, N);
    // t3 = relu(t2_eff @ W3r + invc*m3 + cv3r) -> pooled into praw8 copies
    k_mgemm<64, 32, false, true, true, false, true><<<MG, 256, 0, stream>>>(
        t2b, nullptr, W3r_t, nullptr, cv3r, m3b, row_off, nullptr, s3, q3,
        batch, praw8, N);
    k_finalize<<<1, 32, 0, stream>>>(s3, q3, g3, be3, a3, c3, 32, invN);

    // ---- MLP (sums praw copies, BN3 affine on load) ----
    k_mlp<<<NGRAPH, 128, 0, stream>>>(praw8, a3, c3, gcnt,
                                      Wf1, bf1, Wf2, bf2, Wf3, bf3,
                                      (float*)d_out);
}

// Round 14
// 292.628 us; speedup vs baseline: 1.0832x; 1.0832x over previous
//
#include <hip/hip_runtime.h>
#include <hip/hip_bf16.h>

#define EPSBN 1e-5f
#define NGRAPH 512
#define SCAN_NB 128

typedef __attribute__((ext_vector_type(8))) short bf16x8;
typedef __attribute__((ext_vector_type(4))) float f32x4;

__device__ inline short f2bf(float f) {  // RNE float->bf16
    unsigned u = __builtin_bit_cast(unsigned, f);
    u += 0x7fffu + ((u >> 16) & 1u);
    return (short)(u >> 16);
}
__device__ inline float bf2f(short s) {
    unsigned u = ((unsigned)(unsigned short)s) << 16;
    return __builtin_bit_cast(float, u);
}
// Real XCD id (m09). Correctness-safe uses only: privatized copies summed later.
__device__ inline int xcd_id() {
    int x;
    asm volatile("s_getreg_b32 %0, hwreg(HW_REG_XCC_ID, 0, 4)" : "=s"(x));
    return x & 7;
}

// ---------------------------------------------------------------------------
// CSR build step 1: 8-copy histogram of dst (per-XCD privatized)
// ---------------------------------------------------------------------------
__global__ void __launch_bounds__(256) k_hist8(
    const int* __restrict__ dst, int* __restrict__ hist8, int E, int Npad)
{
    int* h = hist8 + xcd_id() * Npad;
    const int stride = gridDim.x * 256;
    for (int e = blockIdx.x * 256 + threadIdx.x; e < E; e += stride)
        atomicAdd(&h[dst[e]], 1);
}

// scan phase 1: per-block partial sums of (8-copy summed) hist
__global__ void __launch_bounds__(256) k_scan1(
    const int* __restrict__ hist8, int* __restrict__ blocksum, int N, int Npad)
{
    __shared__ int red[256];
    const int C = (N + SCAN_NB - 1) / SCAN_NB;
    const int b = blockIdx.x, t = threadIdx.x;
    const int lo = b * C, hi = min(lo + C, N);
    int s = 0;
    for (int i = lo + t; i < hi; i += 256) {
        int v = 0;
        #pragma unroll
        for (int c = 0; c < 8; c++) v += hist8[c * Npad + i];
        s += v;
    }
    red[t] = s;
    __syncthreads();
    for (int off = 128; off; off >>= 1) {
        if (t < off) red[t] += red[t + off];
        __syncthreads();
    }
    if (t == 0) blocksum[b] = red[0];
}

// scan phase 2: per-block offset from blocksum + local scan -> row_off/cursor
__global__ void __launch_bounds__(256) k_scan3(
    const int* __restrict__ hist8, const int* __restrict__ blocksum,
    int* __restrict__ row_off, int* __restrict__ cursor, int N, int Npad)
{
    __shared__ int red[256];
    __shared__ int boff_s;
    const int C = (N + SCAN_NB - 1) / SCAN_NB;
    const int b = blockIdx.x, t = threadIdx.x;
    const int lo = b * C, hi = min(lo + C, N);
    if (t == 0) {
        int acc = 0;
        for (int i = 0; i < b; i++) acc += blocksum[i];
        boff_s = acc;
        if (b == SCAN_NB - 1) {
            int tot = acc;
            for (int i = b; i < SCAN_NB; i++) tot += blocksum[i];
            row_off[N] = tot;
        }
    }
    const int TC = (C + 255) / 256;
    const int s0 = lo + t * TC;
    const int s1 = min(s0 + TC, hi);
    auto hsum = [&](int i) {
        int v = 0;
        #pragma unroll
        for (int c = 0; c < 8; c++) v += hist8[c * Npad + i];
        return v;
    };
    int s = 0;
    for (int i = s0; i < s1; i++) s += hsum(i);
    red[t] = s;
    __syncthreads();
    for (int off = 1; off < 256; off <<= 1) {
        int u = (t >= off) ? red[t - off] : 0;
        __syncthreads();
        red[t] += u;
        __syncthreads();
    }
    int run = boff_s + red[t] - s;
    for (int i = s0; i < s1; i++) {
        row_off[i] = run;
        cursor[i] = run;
        run += hsum(i);
    }
}

// CSR build step 3: plain grid-stride scatter (measured floor ~55us,
// writeback-bound: 64B HBM burst per random 4B write; NT store made it worse,
// XCD work-partitioning made it much worse — both falsified, R9/R11)
__global__ void __launch_bounds__(256) k_scatter(
    const int* __restrict__ src, const int* __restrict__ dst,
    int* __restrict__ cursor, int* __restrict__ csr, int E)
{
    for (int e = blockIdx.x * 256 + threadIdx.x; e < E; e += gridDim.x * 256) {
        int d = dst[e];
        int p = atomicAdd(&cursor[d], 1);
        csr[p] = src[e];
    }
}

// ---------------------------------------------------------------------------
// per-graph node counts via binary search on sorted batch (no atomics)
// ---------------------------------------------------------------------------
__device__ inline int lbound(const int* __restrict__ a, int n, int v) {
    int lo = 0, hi = n;
    while (lo < hi) {
        int mid = (lo + hi) >> 1;
        if (a[mid] < v) lo = mid + 1; else hi = mid;
    }
    return lo;
}
__global__ void __launch_bounds__(256) k_gcnt_bs(
    const int* __restrict__ batch, float* __restrict__ gcnt, int N)
{
    int g = blockIdx.x * 256 + threadIdx.x;
    if (g < NGRAPH)
        gcnt[g] = (float)(lbound(batch, N, g + 1) - lbound(batch, N, g));
}

// ---------------------------------------------------------------------------
// Gather-aggregate, bf16 rows (16B/lane), fp32 accumulate, bf16 out.
// 4 loads in flight, 2 acc arrays. Measured optimum (R12); wave-per-row
// variant regressed (R13): gather is request-throughput-bound, not
// divergence-bound.
// ---------------------------------------------------------------------------
template <int F>
__global__ void __launch_bounds__(256) k_gatherb(
    const short* __restrict__ feat, const int* __restrict__ row_off,
    const int* __restrict__ csr, short* __restrict__ aggb, int N)
{
    constexpr int LPR = F / 8;
    constexpr int RPB = 256 / LPR;
    const int lane = threadIdx.x % LPR;
    const int rloc = threadIdx.x / LPR;
    const short* fbase = feat + lane * 8;
    for (int row = blockIdx.x * RPB + rloc; row < N; row += gridDim.x * RPB) {
        const int s0 = row_off[row];
        const int s1 = row_off[row + 1];
        float acc0[8], acc1[8];
        #pragma unroll
        for (int i = 0; i < 8; i++) { acc0[i] = 0.f; acc1[i] = 0.f; }
        int p = s0;
        for (; p + 3 < s1; p += 4) {
            int sA = csr[p], sB = csr[p + 1], sC = csr[p + 2], sD = csr[p + 3];
            bf16x8 va = *(const bf16x8*)&fbase[(long long)sA * F];
            bf16x8 vb = *(const bf16x8*)&fbase[(long long)sB * F];
            bf16x8 vc = *(const bf16x8*)&fbase[(long long)sC * F];
            bf16x8 vd = *(const bf16x8*)&fbase[(long long)sD * F];
            #pragma unroll
            for (int i = 0; i < 8; i++) {
                acc0[i] += bf2f(va[i]) + bf2f(vc[i]);
                acc1[i] += bf2f(vb[i]) + bf2f(vd[i]);
            }
        }
        for (; p < s1; p++) {
            int sA = csr[p];
            bf16x8 va = *(const bf16x8*)&fbase[(long long)sA * F];
            #pragma unroll
            for (int i = 0; i < 8; i++) acc0[i] += bf2f(va[i]);
        }
        short o[8];
        #pragma unroll
        for (int i = 0; i < 8; i++) o[i] = f2bf(acc0[i] + acc1[i]);
        *(bf16x8*)&aggb[(long long)row * F + lane * 8] = *(bf16x8*)o;
    }
}

// ---------------------------------------------------------------------------
// fp32 -> bf16 convert
// ---------------------------------------------------------------------------
__global__ void __launch_bounds__(256) k_cvt(
    const float* __restrict__ in, short* __restrict__ out, long long n4)
{
    long long i = (long long)blockIdx.x * 256 + threadIdx.x;
    if (i >= n4) return;
    float4 v = *(const float4*)&in[i * 4];
    short4 o = make_short4(f2bf(v.x), f2bf(v.y), f2bf(v.z), f2bf(v.w));
    *(short4*)&out[i * 4] = o;
}

// ---------------------------------------------------------------------------
// Weight prep (both matrices of a layer in one launch)
// ---------------------------------------------------------------------------
template <int K, int F, bool AFF>
__global__ void __launch_bounds__(64) k_wprep2(
    const float* __restrict__ Wl, const float* __restrict__ Wr,
    const float* __restrict__ a, const float* __restrict__ c,
    const float* __restrict__ bias,
    short* __restrict__ Wlt, short* __restrict__ Wrt,
    float* __restrict__ cvl, float* __restrict__ cvr)
{
    int j = blockIdx.x * 64 + threadIdx.x;
    const bool second = j >= F;
    const int jj = second ? j - F : j;
    if (jj >= F || j >= 2 * F) return;
    const float* W = second ? Wr : Wl;
    short* Wt = second ? Wrt : Wlt;
    float cv = (second && bias) ? bias[jj] : 0.f;
    for (int k = 0; k < K; k++) {
        float w = W[k * F + jj];
        float aa = 1.f;
        if constexpr (AFF) {
            aa = a[k];
            cv += c[k] * w;
        }
        Wt[jj * K + k] = f2bf(aa * w);
    }
    if (second) cvr[jj] = cv; else cvl[jj] = cv;
}

// ---------------------------------------------------------------------------
// MFMA bf16 GEMM with fused epilogue.
//   v = [relu]( A@Wt' + DUAL*invc*(A2@Wt2') + HASBASE*invc*base + cvec )
//   POOL: atomicAdd v into this XCD's praw copy (8-copy privatized)
// ---------------------------------------------------------------------------
template <int K, int FOUT, bool DUAL, bool HASBASE, bool FINAL, bool OUTBF16,
          bool POOL>
__global__ void __launch_bounds__(256) k_mgemm(
    const short* __restrict__ A, const short* __restrict__ A2,
    const short* __restrict__ Wt, const short* __restrict__ Wt2,
    const float* __restrict__ cvec, const short* __restrict__ base,
    const int* __restrict__ row_off, void* outv,
    float* __restrict__ s_out, float* __restrict__ q_out,
    const int* __restrict__ batchp, float* __restrict__ praw8, int N)
{
    constexpr int KS = K / 32;
    constexpr int NCT = FOUT / 16;
    const int lane = threadIdx.x & 63;
    const int wid = threadIdx.x >> 6;
    const int g = lane >> 4;
    const int mi = lane & 15;
    const int RT = (N + 15) >> 4;
    const int nw = gridDim.x * 4;
    float* outf = (float*)outv;
    short* outb = (short*)outv;
    float* pr = nullptr;
    if constexpr (POOL) pr = praw8 + (size_t)xcd_id() * NGRAPH * 32;

    float st_s[FINAL ? NCT : 1];
    float st_q[FINAL ? NCT : 1];
    if constexpr (FINAL) {
        #pragma unroll
        for (int ct = 0; ct < NCT; ct++) { st_s[ct] = 0.f; st_q[ct] = 0.f; }
    }

    for (int rt = blockIdx.x * 4 + wid; rt < RT; rt += nw) {
        const int m0 = rt * 16;
        int arow = m0 + mi;
        if (arow >= N) arow = N - 1;

        bf16x8 af[KS];
        bf16x8 af2[DUAL ? KS : 1];
        const short* ap = A + (long long)arow * K;
        #pragma unroll
        for (int s = 0; s < KS; s++)
            af[s] = *(const bf16x8*)(ap + s * 32 + g * 8);
        if constexpr (DUAL) {
            const short* ap2 = A2 + (long long)arow * K;
            #pragma unroll
            for (int s = 0; s < KS; s++)
                af2[s] = *(const bf16x8*)(ap2 + s * 32 + g * 8);
        }

        float invc[4];
        if constexpr (DUAL || HASBASE) {
            #pragma unroll
            for (int r = 0; r < 4; r++) {
                int row = m0 + 4 * g + r;
                int cnt = 1;
                if (row < N) cnt = max(row_off[row + 1] - row_off[row], 1);
                invc[r] = 1.f / (float)cnt;
            }
        }
        int bidx[4];
        if constexpr (POOL) {
            #pragma unroll
            for (int r = 0; r < 4; r++) {
                int row = m0 + 4 * g + r;
                bidx[r] = (row < N) ? batchp[row] : -1;
            }
        }

        #pragma unroll
        for (int ct = 0; ct < NCT; ct++) {
            f32x4 acc = {0.f, 0.f, 0.f, 0.f};
            f32x4 acc2 = {0.f, 0.f, 0.f, 0.f};
            const short* bp = Wt + (long long)(ct * 16 + mi) * K;
            #pragma unroll
            for (int s = 0; s < KS; s++) {
                bf16x8 bf = *(const bf16x8*)(bp + s * 32 + g * 8);
                acc = __builtin_amdgcn_mfma_f32_16x16x32_bf16(af[s], bf, acc, 0, 0, 0);
                if constexpr (DUAL) {
                    bf16x8 bf2 = *(const bf16x8*)(Wt2 + (long long)(ct * 16 + mi) * K + s * 32 + g * 8);
                    acc2 = __builtin_amdgcn_mfma_f32_16x16x32_bf16(af2[s], bf2, acc2, 0, 0, 0);
                }
            }
            float cv = cvec[ct * 16 + mi];
            float sl = 0.f, ql = 0.f;
            #pragma unroll
            for (int r = 0; r < 4; r++) {
                int row = m0 + 4 * g + r;
                if (row < N) {
                    float v = acc[r] + cv;
                    if constexpr (DUAL) v = fmaf(invc[r], acc2[r], v);
                    if constexpr (HASBASE)
                        v = fmaf(invc[r], bf2f(base[(long long)row * FOUT + ct * 16 + mi]), v);
                    if constexpr (FINAL) v = fmaxf(v, 0.f);
                    if constexpr (POOL) {
                        atomicAdd(&pr[bidx[r] * FOUT + ct * 16 + mi], v);
                    } else if constexpr (OUTBF16) {
                        outb[(long long)row * FOUT + ct * 16 + mi] = f2bf(v);
                    } else {
                        outf[(long long)row * FOUT + ct * 16 + mi] = v;
                    }
                    if constexpr (FINAL) { sl += v; ql += v * v; }
                }
            }
            if constexpr (FINAL) {
                sl += __shfl_xor(sl, 16, 64);
                sl += __shfl_xor(sl, 32, 64);
                ql += __shfl_xor(ql, 16, 64);
                ql += __shfl_xor(ql, 32, 64);
                st_s[ct] += sl;
                st_q[ct] += ql;
            }
        }
    }

    if constexpr (FINAL) {
        __shared__ float redS[4][NCT][16];
        __shared__ float redQ[4][NCT][16];
        if (lane < 16) {
            #pragma unroll
            for (int ct = 0; ct < NCT; ct++) {
                redS[wid][ct][lane] = st_s[ct];
                redQ[wid][ct][lane] = st_q[ct];
            }
        }
        __syncthreads();
        if (wid == 0 && lane < 16) {
            #pragma unroll
            for (int ct = 0; ct < NCT; ct++) {
                float s = redS[0][ct][lane] + redS[1][ct][lane] +
                          redS[2][ct][lane] + redS[3][ct][lane];
                float q = redQ[0][ct][lane] + redQ[1][ct][lane] +
                          redQ[2][ct][lane] + redQ[3][ct][lane];
                atomicAdd(&s_out[ct * 16 + lane], s);
                atomicAdd(&q_out[ct * 16 + lane], q);
            }
        }
    }
}

// ---------------------------------------------------------------------------
// BN affine finalize
// ---------------------------------------------------------------------------
__global__ void k_finalize(const float* __restrict__ s, const float* __restrict__ q,
                           const float* __restrict__ g, const float* __restrict__ be,
                           float* __restrict__ a, float* __restrict__ c,
                           int F, float invN)
{
    int j = threadIdx.x;
    if (j < F) {
        float mu = s[j] * invN;
        float var = q[j] * invN - mu * mu;
        float aj = g[j] / sqrtf(var + EPSBN);
        a[j] = aj;
        c[j] = be[j] - mu * aj;
    }
}

// ---------------------------------------------------------------------------
// Per-graph MLP (sums 8 praw copies, applies BN3 affine on load)
// ---------------------------------------------------------------------------
__global__ void __launch_bounds__(128) k_mlp(
    const float* __restrict__ praw8, const float* __restrict__ a3,
    const float* __restrict__ c3, const float* __restrict__ gcnt,
    const float* __restrict__ Wf1, const float* __restrict__ bf1,
    const float* __restrict__ Wf2, const float* __restrict__ bf2,
    const float* __restrict__ Wf3, const float* __restrict__ bf3,
    float* __restrict__ out)
{
    __shared__ float p[32], h1[128], h2[64];
    int g = blockIdx.x, t = threadIdx.x;
    if (t < 32) {
        float s = 0.f;
        #pragma unroll
        for (int c = 0; c < 8; c++)
            s += praw8[(size_t)c * NGRAPH * 32 + g * 32 + t];
        p[t] = a3[t] * s + gcnt[g] * c3[t];
    }
    __syncthreads();
    {
        float acc = bf1[t];
        #pragma unroll
        for (int k = 0; k < 32; k++) acc += p[k] * Wf1[k * 128 + t];
        h1[t] = fmaxf(acc, 0.f);
    }
    __syncthreads();
    if (t < 64) {
        float acc = bf2[t];
        #pragma unroll
        for (int k = 0; k < 128; k++) acc += h1[k] * Wf2[k * 64 + t];
        h2[t] = fmaxf(acc, 0.f);
    }
    __syncthreads();
    if (t < 2) {
        float acc = bf3[t];
        #pragma unroll
        for (int k = 0; k < 64; k++) acc += h2[k] * Wf3[k * 2 + t];
        out[g * 2 + t] = acc;
    }
}

// ---------------------------------------------------------------------------
extern "C" void kernel_launch(void* const* d_in, const int* in_sizes, int n_in,
                              void* d_out, int out_size, void* d_ws, size_t ws_size,
                              hipStream_t stream)
{
    const float* x     = (const float*)d_in[0];
    const int*   ei    = (const int*)d_in[1];
    const int*   batch = (const int*)d_in[2];
    const float* W1l = (const float*)d_in[3];
    const float* b1  = (const float*)d_in[4];
    const float* W1r = (const float*)d_in[5];
    const float* g1  = (const float*)d_in[6];
    const float* be1 = (const float*)d_in[7];
    const float* W2l = (const float*)d_in[8];
    const float* b2  = (const float*)d_in[9];
    const float* W2r = (const float*)d_in[10];
    const float* g2  = (const float*)d_in[11];
    const float* be2 = (const float*)d_in[12];
    const float* W3l = (const float*)d_in[13];
    const float* b3  = (const float*)d_in[14];
    const float* W3r = (const float*)d_in[15];
    const float* g3  = (const float*)d_in[16];
    const float* be3 = (const float*)d_in[17];
    const float* Wf1 = (const float*)d_in[18];
    const float* bf1 = (const float*)d_in[19];
    const float* Wf2 = (const float*)d_in[20];
    const float* bf2 = (const float*)d_in[21];
    const float* Wf3 = (const float*)d_in[22];
    const float* bf3 = (const float*)d_in[23];

    const int N = in_sizes[0] / 64;
    const int E = in_sizes[1] / 2;
    const int Npad = (N + 255) & ~255;
    const int* src = ei;
    const int* dst = ei + E;

    // ---- workspace layout (zoned aliasing; zeroed accumulators contiguous) --
    char* ws = (char*)d_ws;
    size_t off = 0;
    auto alloc = [&](size_t bytes) {
        size_t o = off;
        off += (bytes + 511) & ~(size_t)511;
        return o;
    };
    const size_t o_rowoff = alloc((size_t)(N + 1) * 4);
    const size_t o_cursor = alloc((size_t)N * 4);
    const size_t o_bsum   = alloc(SCAN_NB * 4);
    const size_t o_csr    = alloc((size_t)E * 4);
    const size_t o_zoneB  = alloc((size_t)N * 128);  // xb -> y2b (bf16)
    const size_t o_zoneC  = alloc((size_t)N * 128);  // aggb -> t2b (bf16)
    const size_t o_zoneD  = alloc((size_t)N * 256);  // t1b -> y3b (bf16)
    const size_t o_zoneE  = alloc((size_t)N * 128);  // m2b -> m3b (bf16)
    const size_t o_aff    = alloc(448 * 4);
    const size_t o_cvec   = alloc(512 * 4);
    const size_t o_wt     = alloc((8192 * 4 + 2048 * 2) * 2);
    const size_t o_gcnt   = alloc((size_t)NGRAPH * 4);      // overwritten fully
    // ---- zero zone (single memset) ----
    const size_t o_zero0  = off;
    const size_t o_hist8  = alloc((size_t)Npad * 8 * 4);
    const size_t o_stats  = alloc(448 * 4);
    const size_t o_praw8  = alloc((size_t)NGRAPH * 32 * 4 * 8);
    const size_t zero_len = off - o_zero0;
    (void)ws_size;

    int* row_off = (int*)(ws + o_rowoff);
    int* hist8   = (int*)(ws + o_hist8);
    int* cursor  = (int*)(ws + o_cursor);
    int* bsum    = (int*)(ws + o_bsum);
    int* csr     = (int*)(ws + o_csr);
    short* xb   = (short*)(ws + o_zoneB);
    short* y2b  = (short*)(ws + o_zoneB);       // after xb dead
    short* aggb = (short*)(ws + o_zoneC);
    short* t2b  = (short*)(ws + o_zoneC);       // after aggb dead
    short* t1b  = (short*)(ws + o_zoneD);
    short* y3b  = (short*)(ws + o_zoneD);       // after t1b dead
    short* m2b  = (short*)(ws + o_zoneE);
    short* m3b  = (short*)(ws + o_zoneE);       // after m2b dead
    float* praw8 = (float*)(ws + o_praw8);
    float* gcnt  = (float*)(ws + o_gcnt);
    float* s1 = (float*)(ws + o_stats);
    float* q1 = s1 + 128;
    float* s2 = q1 + 128;
    float* q2 = s2 + 64;
    float* s3 = q2 + 64;
    float* q3 = s3 + 32;
    float* a1 = (float*)(ws + o_aff);
    float* c1 = a1 + 128;
    float* a2 = c1 + 128;
    float* c2 = a2 + 64;
    float* a3 = c2 + 64;
    float* c3 = a3 + 32;
    float* cv1l = (float*)(ws + o_cvec);         // dummy
    float* cv1r = cv1l + 128;
    float* cv2l = cv1r + 128;
    float* cv2r = cv2l + 64;
    float* cv3l = cv2r + 64;
    float* cv3r = cv3l + 32;
    short* W1l_t = (short*)(ws + o_wt);          // 128x64
    short* W1r_t = W1l_t + 8192;
    short* W2l_t = W1r_t + 8192;
    short* W2r_t = W2l_t + 8192;
    short* W3l_t = W2r_t + 8192;
    short* W3r_t = W3l_t + 2048;

    const float invN = 1.0f / (float)N;
    const int MG = 512;

    // ---- zero accumulators (one memset, ~2.4 MB) ----
    hipMemsetAsync(ws + o_zero0, 0, zero_len, stream);

    // ---- CSR build ----
    k_hist8<<<2048, 256, 0, stream>>>(dst, hist8, E, Npad);
    k_scan1<<<SCAN_NB, 256, 0, stream>>>(hist8, bsum, N, Npad);
    k_scan3<<<SCAN_NB, 256, 0, stream>>>(hist8, bsum, row_off, cursor, N, Npad);
    k_scatter<<<2048, 256, 0, stream>>>(src, dst, cursor, csr, E);
    k_gcnt_bs<<<2, 256, 0, stream>>>(batch, gcnt, N);

    // ---- prep: x->bf16, layer-1 weights ----
    k_cvt<<<(int)(((long long)N * 16 + 255) / 256), 256, 0, stream>>>(
        x, xb, (long long)N * 16);
    k_wprep2<64, 128, false><<<4, 64, 0, stream>>>(
        W1l, W1r, nullptr, nullptr, b1, W1l_t, W1r_t, cv1l, cv1r);

    // ---- layer 1: t1 = relu(x@W1r + invc*(agg@W1l) + b1) ----
    k_gatherb<64><<<(N + 31) / 32, 256, 0, stream>>>(
        xb, row_off, csr, aggb, N);
    k_mgemm<64, 128, true, false, true, true, false><<<MG, 256, 0, stream>>>(
        xb, aggb, W1r_t, W1l_t, cv1r, nullptr, row_off, t1b, s1, q1,
        nullptr, nullptr, N);
    k_finalize<<<1, 128, 0, stream>>>(s1, q1, g1, be1, a1, c1, 128, invN);

    // ---- layer 2 ----
    k_wprep2<128, 64, true><<<2, 64, 0, stream>>>(
        W2l, W2r, a1, c1, b2, W2l_t, W2r_t, cv2l, cv2r);
    k_mgemm<128, 64, false, false, false, true, false><<<MG, 256, 0, stream>>>(
        t1b, nullptr, W2l_t, nullptr, cv2l, nullptr, row_off, y2b,
        nullptr, nullptr, nullptr, nullptr, N);
    k_gatherb<64><<<(N + 31) / 32, 256, 0, stream>>>(
        y2b, row_off, csr, m2b, N);
    k_mgemm<128, 64, false, true, true, true, false><<<MG, 256, 0, stream>>>(
        t1b, nullptr, W2r_t, nullptr, cv2r, m2b, row_off, t2b, s2, q2,
        nullptr, nullptr, N);
    k_finalize<<<1, 64, 0, stream>>>(s2, q2, g2, be2, a2, c2, 64, invN);

    // ---- layer 3 ----
    k_wprep2<64, 32, true><<<1, 64, 0, stream>>>(
        W3l, W3r, a2, c2, b3, W3l_t, W3r_t, cv3l, cv3r);
    k_mgemm<64, 32, false, false, false, true, false><<<MG, 256, 0, stream>>>(
        t2b, nullptr, W3l_t, nullptr, cv3l, nullptr, row_off, y3b,
        nullptr, nullptr, nullptr, nullptr, N);
    k_gatherb<32><<<(N + 63) / 64, 256, 0, stream>>>(
        y3b, row_off, csr, m3b, N);
    // t3 = relu(t2_eff @ W3r + invc*m3 + cv3r) -> pooled into praw8 copies
    k_mgemm<64, 32, false, true, true, false, true><<<MG, 256, 0, stream>>>(
        t2b, nullptr, W3r_t, nullptr, cv3r, m3b, row_off, nullptr, s3, q3,
        batch, praw8, N);
    k_finalize<<<1, 32, 0, stream>>>(s3, q3, g3, be3, a3, c3, 32, invN);

    // ---- MLP (sums praw copies, BN3 affine on load) ----
    k_mlp<<<NGRAPH, 128, 0, stream>>>(praw8, a3, c3, gcnt,
                                      Wf1, bf1, Wf2, bf2, Wf3, bf3,
                                      (float*)d_out);
}